// Round 4
// baseline (780.008 us; speedup 1.0000x reference)
//
#include <hip/hip_runtime.h>
#include <hip/hip_bf16.h>
#include <stdint.h>

// GRU layer: B=32, L=48, N=325, D=128. BN=10400 independent sequences, scan over L.
// Weights live in registers as MFMA B-fragments (loaded once), h is fp32 in regs
// for the elementwise update and bf16 in (double-buffered) LDS for the recurrent
// GEMM. bf16 MFMA 16x16x32. X register-staged one step ahead w/ fp32->bf16 cvt at
// stage time; LDS-only step barrier (lgkmcnt, no vmcnt drain).
//
// v4 change: MT 48 -> 16 (BN = 650*16 exactly; all tail masks/clamps deleted).
// v3's counters showed VALU 36.5% + MFMA 24.8% + LDS ~30% summing to ~92% of
// elapsed with OccupancyPercent 18.6 (ONE 8-wave block per CU): the pipes never
// overlap because all waves of the single resident block move phase-lockstep
// between barriers. MT=16 gives 650 blocks at <=128 VGPR (__launch_bounds__(512,4))
// and 17.4 KB LDS -> TWO independent blocks per CU, so one block's VALU/trans
// phase overlaps the other's MFMA/LDS phase. Worst-case per-CU load also drops
// (48 seqs = 3x16 vs 64 = 2x32 for an MT=32 split).

constexpr int Bdim = 32;
constexpr int Ldim = 48;
constexpr int Nseq = 325;
constexpr int Ddim = 128;
constexpr int BN   = Bdim * Nseq;          // 10400
constexpr int MT   = 16;                   // sequences per block (1 m-tile of 16)
constexpr int NMT  = MT / 16;              // m-tiles per block
constexpr int NBLK = BN / MT;              // 650 (exact)
static_assert(BN % MT == 0, "no tail");
constexpr int RPW  = MT / 8;               // X rows staged per wave
constexpr int RS   = 136;                  // h row stride, bf16 elems (68 dwords == 4 mod 32)
constexpr int XR   = 272;                  // x row stride BYTES (136 bf16)
constexpr int HBUF_B = 2 * MT * RS * 2;    // 8704 B
constexpr int XBUF_B = MT * XR;            // 4352 B per buffer
constexpr int SMEM_B = HBUF_B + 2 * XBUF_B;// 17408 B

typedef __bf16 bf16;
typedef __bf16 bf16x2 __attribute__((ext_vector_type(2)));
typedef __bf16 bf16x8 __attribute__((ext_vector_type(8)));
typedef float  floatx2 __attribute__((ext_vector_type(2)));
typedef float  floatx4 __attribute__((ext_vector_type(4)));
typedef float  floatx8 __attribute__((ext_vector_type(8)));

__device__ __forceinline__ float fast_sigmoid(float x) {
    return __builtin_amdgcn_rcpf(1.f + __expf(-x));
}
__device__ __forceinline__ float fast_tanh(float x) {
    const float e = __expf(-2.f * __builtin_fabsf(x));
    const float t = (1.f - e) * __builtin_amdgcn_rcpf(1.f + e);
    return __builtin_copysignf(t, x);
}

// Barrier with LDS-visibility only: does NOT drain vmcnt, so output stores and
// prefetch loads stay in flight across steps. sched_barrier(0) fences keep the
// compiler from hoisting LDS ops across the inline-asm wait (rule #18).
__device__ __forceinline__ void sync_lds_only() {
    __builtin_amdgcn_sched_barrier(0);
    asm volatile("s_waitcnt lgkmcnt(0)" ::: "memory");
    __builtin_amdgcn_sched_barrier(0);
    __builtin_amdgcn_s_barrier();
    __builtin_amdgcn_sched_barrier(0);
}

// true  -> buffers are float32 (reference dtype)
// false -> buffers are bfloat16
__device__ __forceinline__ bool detect_f32(const void* wih) {
    const bf16* p = (const bf16*)wih;
    bool f32 = false;
#pragma unroll
    for (int i = 0; i < 128; i += 2) {
        const float v = __builtin_fabsf((float)p[i]);
        if (!(v <= 0.125f)) f32 = true;   // NaN also lands here
    }
    return f32;
}

template <bool F32>
__device__ __forceinline__ bf16x8 load8(const void* base, size_t off) {
    if constexpr (F32) {
        const floatx8 v = *(const floatx8*)((const float*)base + off);
        return __builtin_convertvector(v, bf16x8);
    } else {
        return *(const bf16x8*)((const bf16*)base + off);
    }
}
template <bool F32>
__device__ __forceinline__ float lds1(const void* base, int i) {
    if constexpr (F32) return ((const float*)base)[i];
    else               return (float)((const bf16*)base)[i];
}

template <bool F32>
__device__ __forceinline__ void gru_body(
    const void* __restrict__ X, const void* __restrict__ Wih,
    const void* __restrict__ Whh, const void* __restrict__ bih,
    const void* __restrict__ bhh, void* __restrict__ out,
    char* __restrict__ smem)
{
    const int tid  = threadIdx.x;
    const int wave = tid >> 6;       // 0..7 : owns d-cols [wave*16, wave*16+16)
    const int lane = tid & 63;
    const int l16  = lane & 15;
    const int q    = lane >> 4;      // quad 0..3
    const int t0   = blockIdx.x * MT;
    const int dcol = wave * 16 + l16;

    bf16* hbuf = (bf16*)smem;                 // [2][MT*RS]
    char* xbuf = smem + HBUF_B;               // [2][MT*XR] bf16 rows

    // Weight B-fragments (B[k=q*8+j][n=lane&15]) -> per lane one contiguous 8-elem run.
    bf16x8 wih_f[3][4], whh_f[3][4];
#pragma unroll
    for (int g = 0; g < 3; ++g) {
        const size_t rowoffw = (size_t)(g * 128 + dcol) * Ddim + q * 8;
#pragma unroll
        for (int kk = 0; kk < 4; ++kk) {
            wih_f[g][kk] = load8<F32>(Wih, rowoffw + kk * 32);
            whh_f[g][kk] = load8<F32>(Whh, rowoffw + kk * 32);
        }
    }

    const float bias_r  = lds1<F32>(bih, dcol)       + lds1<F32>(bhh, dcol);
    const float bias_z  = lds1<F32>(bih, 128 + dcol) + lds1<F32>(bhh, 128 + dcol);
    const float bias_in = lds1<F32>(bih, 256 + dcol);
    const float bias_hn = lds1<F32>(bhh, 256 + dcol);

    // --- X staging: this wave owns block-local rows [wave*RPW, wave*RPW+RPW).
    // Per row, each lane loads elems [2*lane, 2*lane+1] (dwordx2 fp32 / dword bf16),
    // converts to bf16 and ds_write_b32's them into the padded bf16 row.
    const int   srow0 = wave * RPW;
    const char* Xc    = (const char*)X;
    const uint32_t lstride = (uint32_t)(Nseq * Ddim) * (F32 ? 4u : 2u);
    uint32_t rowoff[RPW];
#pragma unroll
    for (int i = 0; i < RPW; ++i) {
        const int t = t0 + srow0 + i;          // always < BN (exact tiling)
        const int b = t / Nseq;
        const int n = t - b * Nseq;
        rowoff[i] = (uint32_t)(b * (Ldim * Nseq) + n) * Ddim * (F32 ? 4u : 2u)
                  + ((uint32_t)lane << (F32 ? 3 : 2));
    }

    floatx2  vf[RPW];
    uint32_t vb[RPW];
    auto stage_load = [&](int l) {
        const char* Xl = Xc + (uint32_t)l * lstride;
#pragma unroll
        for (int i = 0; i < RPW; ++i) {
            if constexpr (F32) vf[i] = *(const floatx2*)(Xl + rowoff[i]);
            else               vb[i] = *(const uint32_t*)(Xl + rowoff[i]);
        }
    };
    auto stage_write = [&](char* xb) {
#pragma unroll
        for (int i = 0; i < RPW; ++i) {
            uint32_t w;
            if constexpr (F32) {
                union { bf16x2 h; uint32_t u; } cv;
                cv.h = __builtin_convertvector(vf[i], bf16x2);
                w = cv.u;
            } else {
                w = vb[i];
            }
            *(uint32_t*)(xb + (srow0 + i) * XR + (lane << 2)) = w;
        }
    };

    // --- Output store bases (incremental; r-offset folds into store immediate).
    constexpr size_t esz = F32 ? 4 : 2;
    const size_t OSTEP = (size_t)BN * Ddim * esz;
    size_t obyte[NMT];
#pragma unroll
    for (int mt = 0; mt < NMT; ++mt) {
        const int trow = t0 + mt * 16 + q * 4;
        obyte[mt] = ((size_t)trow * Ddim + dcol) * esz;
    }

    for (int i = tid; i < MT * RS; i += 512) hbuf[i] = (bf16)0.f;
    stage_load(0);
    stage_write(xbuf);
    floatx4 hreg[NMT];
#pragma unroll
    for (int mt = 0; mt < NMT; ++mt) hreg[mt] = floatx4{0.f, 0.f, 0.f, 0.f};
    __syncthreads();                           // one-time full drain; l=0 tile resident

    int cur = 0;
    for (int l = 0; l < Ldim; ++l) {
        const char* xc = xbuf + cur * XBUF_B;
        const bf16* hc = hbuf + cur * (MT * RS);

        // 1) gi A-fragments from staged bf16 X in LDS.
        bf16x8 xf[NMT][4];
#pragma unroll
        for (int mt = 0; mt < NMT; ++mt)
#pragma unroll
            for (int kk = 0; kk < 4; ++kk)
                xf[mt][kk] = *(const bf16x8*)(xc + (mt * 16 + l16) * XR + kk * 64 + q * 16);

        // 2) Issue next timestep's X loads into registers; the cvt at stage_write
        //    (end of step) is the first use, so the HBM latency hides under the
        //    GEMMs + elementwise. (Last iter re-loads l=47: L3-hit, discarded.)
        const int lp = (l + 1 < Ldim) ? (l + 1) : (Ldim - 1);
        stage_load(lp);

        floatx4 acc_r[NMT], acc_z[NMT], acc_in[NMT], acc_hn[NMT];
#pragma unroll
        for (int mt = 0; mt < NMT; ++mt) {
            acc_r[mt]  = floatx4{bias_r,  bias_r,  bias_r,  bias_r};
            acc_z[mt]  = floatx4{bias_z,  bias_z,  bias_z,  bias_z};
            acc_in[mt] = floatx4{bias_in, bias_in, bias_in, bias_in};
            acc_hn[mt] = floatx4{bias_hn, bias_hn, bias_hn, bias_hn};
        }

        // 3) gh GEMM: h_prev (LDS bf16) @ Whh^T
#pragma unroll
        for (int kk = 0; kk < 4; ++kk) {
#pragma unroll
            for (int mt = 0; mt < NMT; ++mt) {
                const bf16x8 af = *(const bf16x8*)&hc[(mt * 16 + l16) * RS + kk * 32 + q * 8];
                acc_r[mt]  = __builtin_amdgcn_mfma_f32_16x16x32_bf16(af, whh_f[0][kk], acc_r[mt],  0, 0, 0);
                acc_z[mt]  = __builtin_amdgcn_mfma_f32_16x16x32_bf16(af, whh_f[1][kk], acc_z[mt],  0, 0, 0);
                acc_hn[mt] = __builtin_amdgcn_mfma_f32_16x16x32_bf16(af, whh_f[2][kk], acc_hn[mt], 0, 0, 0);
            }
        }
        // 4) gi GEMM: x_l @ Wih^T (A-frags already in registers)
#pragma unroll
        for (int kk = 0; kk < 4; ++kk) {
#pragma unroll
            for (int mt = 0; mt < NMT; ++mt) {
                acc_r[mt]  = __builtin_amdgcn_mfma_f32_16x16x32_bf16(xf[mt][kk], wih_f[0][kk], acc_r[mt],  0, 0, 0);
                acc_z[mt]  = __builtin_amdgcn_mfma_f32_16x16x32_bf16(xf[mt][kk], wih_f[1][kk], acc_z[mt],  0, 0, 0);
                acc_in[mt] = __builtin_amdgcn_mfma_f32_16x16x32_bf16(xf[mt][kk], wih_f[2][kk], acc_in[mt], 0, 0, 0);
            }
        }

        // 5) GRU update in registers (C layout: row = q*4 + r, col = dcol).
        const int nxt = cur ^ 1;
        bf16* hn = hbuf + nxt * (MT * RS);
#pragma unroll
        for (int mt = 0; mt < NMT; ++mt) {
            floatx4 hnew;
#pragma unroll
            for (int r = 0; r < 4; ++r) {
                const float rg = fast_sigmoid(acc_r[mt][r]);
                const float zg = fast_sigmoid(acc_z[mt][r]);
                const float ng = fast_tanh(acc_in[mt][r] + rg * acc_hn[mt][r]);
                const float h  = ng + zg * (hreg[mt][r] - ng);   // (1-z)*ng + z*h
                hnew[r] = h;
                hn[(mt * 16 + q * 4 + r) * RS + dcol] = (bf16)h;
                char* op = (char*)out + obyte[mt] + (size_t)(r * Ddim) * esz;
                if constexpr (F32) *(float*)op = h;
                else               *(bf16*)op  = (bf16)h;
            }
            hreg[mt]  = hnew;
            obyte[mt] += OSTEP;
        }

        // 6) Convert + write the prefetched X tile into the other buffer.
        stage_write(xbuf + nxt * XBUF_B);

        // 7) LDS-only barrier: stores/loads in flight are NOT drained.
        sync_lds_only();
        cur = nxt;
    }
}

__global__ __launch_bounds__(512, 4) void gru_rnn_kernel(
    const void* __restrict__ X, const void* __restrict__ Wih,
    const void* __restrict__ Whh, const void* __restrict__ bih,
    const void* __restrict__ bhh, void* __restrict__ out)
{
    __shared__ __align__(16) char smem[SMEM_B];
    if (detect_f32(Wih)) gru_body<true >(X, Wih, Whh, bih, bhh, out, smem);
    else                 gru_body<false>(X, Wih, Whh, bih, bhh, out, smem);
}

extern "C" void kernel_launch(void* const* d_in, const int* in_sizes, int n_in,
                              void* d_out, int out_size, void* d_ws, size_t ws_size,
                              hipStream_t stream) {
    hipLaunchKernelGGL(gru_rnn_kernel, dim3(NBLK), dim3(512), 0, stream,
                       d_in[0], d_in[1], d_in[2], d_in[3], d_in[4], d_out);
}